// Round 3
// baseline (15183.160 us; speedup 1.0000x reference)
//
#include <hip/hip_runtime.h>
#include <stdint.h>

typedef unsigned short u16;
typedef unsigned int u32;
typedef __attribute__((ext_vector_type(8))) short bf16x8;
typedef __attribute__((ext_vector_type(4))) float f32x4;

#define TT 1024
#define BB 64
#define EE 256
#define HH 512
#define GG 2048   // 4H
#define NWG 32    // scan workgroups, 16 h-units each

__device__ __forceinline__ float bf2f(u16 h) {
  union { u32 i; float f; } v; v.i = ((u32)h) << 16; return v.f;
}
__device__ __forceinline__ u16 f2bf(float f) {
  union { float f; u32 i; } v; v.f = f;
  u32 b = v.i;
  return (u16)((b + 0x7fffu + ((b >> 16) & 1u)) >> 16);
}
__device__ __forceinline__ float sigm(float x) {
  return 1.f / (1.f + __expf(-x));
}
__device__ __forceinline__ float tanhfast(float x) {
  float e = __expf(2.f * x);
  return 1.f - 2.f / (e + 1.f);
}
// tagged h-cell position (frag order): lane=(b&15)|(kOct<<4), j=u&7
__device__ __forceinline__ int cellpos(int b, int u) {
  return ((((b >> 4) * 16 + (u >> 5)) * 64) +
          ((b & 15) | (((u >> 3) & 3) << 4))) * 8 + (u & 7);
}

// ---------------------------------------------------------------------------
// Kernel 1: xz[t][col][b] bf16 = (emb[x[:,t]] @ kernel) + bias, via MFMA.
// Grid: 1024 (one t per WG), block 256 (4 waves; wave w owns m-tile w).
// A-frags (emb rows, K=256) in regs; B staged frag-ordered in LDS per
// 256-col block (8 blocks). D map: col=l&15 (n), row=(l>>4)*4+reg (m).
// ---------------------------------------------------------------------------
__global__ __launch_bounds__(256) void xz_gemm_mfma(
    const int* __restrict__ x, const float* __restrict__ emb,
    const float* __restrict__ Wk, const float* __restrict__ bias,
    u16* __restrict__ xz) {
  extern __shared__ char sm1[];
  bf16x8* Bl = (bf16x8*)sm1;   // [8192] frags: (nt*8+ks)*64 + lane
  __shared__ int xidx[64];
  const int tid = threadIdx.x;
  const int t = blockIdx.x;
  const int w = tid >> 6, l = tid & 63;
  if (tid < 64) xidx[tid] = x[(size_t)tid * TT + t];
  __syncthreads();

  const int row = w * 16 + (l & 15);
  const int xid = xidx[row];
  bf16x8 af[8];
#pragma unroll
  for (int ks = 0; ks < 8; ++ks) {
    int k0 = ks * 32 + ((l >> 4) << 3);
    const float4* p = (const float4*)(emb + (size_t)xid * EE + k0);
    float4 a0 = p[0], a1 = p[1];
    bf16x8 v;
    v[0] = (short)f2bf(a0.x); v[1] = (short)f2bf(a0.y);
    v[2] = (short)f2bf(a0.z); v[3] = (short)f2bf(a0.w);
    v[4] = (short)f2bf(a1.x); v[5] = (short)f2bf(a1.y);
    v[6] = (short)f2bf(a1.z); v[7] = (short)f2bf(a1.w);
    af[ks] = v;
  }

  for (int nb = 0; nb < 8; ++nb) {
    __syncthreads();  // previous block's ds_reads done before overwrite
    for (int idx = tid; idx < 8192; idx += 256) {
      int nt = idx >> 9, ks = (idx >> 6) & 7, l2 = idx & 63;
      int col = nb * 256 + nt * 16 + (l2 & 15);
      int kb = ks * 32 + ((l2 >> 4) << 3);
      bf16x8 v;
#pragma unroll
      for (int j = 0; j < 8; ++j)
        v[j] = (short)f2bf(Wk[(size_t)(kb + j) * GG + col]);
      Bl[idx] = v;
    }
    __syncthreads();
#pragma unroll 2
    for (int nt = 0; nt < 16; ++nt) {
      f32x4 acc = {0.f, 0.f, 0.f, 0.f};
#pragma unroll
      for (int ks = 0; ks < 8; ++ks)
        acc = __builtin_amdgcn_mfma_f32_16x16x32_bf16(
            af[ks], Bl[(nt * 8 + ks) * 64 + l], acc, 0, 0, 0);
      int col = nb * 256 + nt * 16 + (l & 15);
      float bj = bias[col];
      int b0 = w * 16 + ((l >> 4) << 2);
      u16 o0 = f2bf(acc[0] + bj), o1 = f2bf(acc[1] + bj);
      u16 o2 = f2bf(acc[2] + bj), o3 = f2bf(acc[3] + bj);
      u32* dst = (u32*)(xz + ((size_t)t * GG + col) * BB + b0);
      dst[0] = (u32)o0 | ((u32)o1 << 16);
      dst[1] = (u32)o2 | ((u32)o3 << 16);
    }
  }
}

// ---------------------------------------------------------------------------
// Kernel 2: persistent MFMA LSTM scan, tagged-word dataflow (no flags, no
// fences). h-cell u32 = (bf16 h)<<16 | ((t+1)&0xffff). Producers: relaxed
// agent atomic stores (-> MALL). Consumers: cooperative stage of all 32768
// cells via relaxed agent atomic loads + tag retry -> LDS -> ds_read frags.
// h-buffers: t=0 -> hinit (ws slack); t>=1 -> carved from consumed xz
// slices: hbuf(tau)=xz slice tau-2 first 128KB (tau>=2), hbuf(1)=slice 0
// second 128KB. Safety: a WG writes hbuf only after observing all tags of
// the previous h -> every WG consumed that xz slice (h(0) publish is
// explicitly ordered after xz[0] prefetch retirement via vmcnt(0)).
// ---------------------------------------------------------------------------
__global__ __launch_bounds__(512, 2) void lstm_scan3(
    const int* __restrict__ x, const float* __restrict__ h0,
    const float* __restrict__ c0, const float* __restrict__ rec,
    u16* __restrict__ xz, float* __restrict__ out, u32* __restrict__ hinit) {
  extern __shared__ char sm2[];
  u16* A_lds = (u16*)sm2;             // [32768] cells, frag-linear
  u32* xmask = (u32*)(sm2 + 65536);   // [64][32]
  const int tid = threadIdx.x;
  const int wv = tid >> 6, l = tid & 63;
  const int w = blockIdx.x;
  const int U0 = w * 16;
  const int mt = wv & 3, ntp = wv >> 2;
  const int q = l & 3;
  const int b = mt * 16 + ((l >> 4) << 2) + q;
  const int uoff = (l >> 2) & 3;
  const int u0g = U0 + (2 * ntp + 0) * 4 + uoff;
  const int u1g = U0 + (2 * ntp + 1) * 4 + uoff;
  const int col0 = q * 512 + u0g;
  const int col1 = q * 512 + u1g;

  // --- B fragments (R slice) into registers, once ---
  bf16x8 bfr0[16], bfr1[16];
#pragma unroll
  for (int ks = 0; ks < 16; ++ks) {
    int kbase = ks * 32 + ((l >> 4) << 3);
#pragma unroll
    for (int j = 0; j < 8; ++j) {
      bfr0[ks][j] = (short)f2bf(rec[(size_t)(kbase + j) * GG + col0]);
      bfr1[ks][j] = (short)f2bf(rec[(size_t)(kbase + j) * GG + col1]);
    }
  }
  // --- x bitmask in LDS ---
  for (int i = tid; i < 2048; i += 512) {
    int bb = i >> 5, tw = i & 31;
    u32 mword = 0;
    for (int j = 0; j < 32; ++j)
      mword |= (x[(size_t)bb * TT + tw * 32 + j] != 0 ? 1u : 0u) << j;
    xmask[bb * 32 + tw] = mword;
  }
  float creg0 = c0[(size_t)b * HH + u0g];
  float creg1 = c0[(size_t)b * HH + u1g];
  float hreg0 = h0[(size_t)b * HH + u0g];
  float hreg1 = h0[(size_t)b * HH + u1g];
  __syncthreads();  // xmask ready

  // --- preload xz for t=0; mask word 0 ---
  float xzc[8];
#pragma unroll
  for (int g = 0; g < 4; ++g) {
    xzc[g]     = bf2f(xz[((size_t)0 * GG + g * HH + u0g) * BB + b]);
    xzc[4 + g] = bf2f(xz[((size_t)0 * GG + g * HH + u1g) * BB + b]);
  }
  u32 mw = xmask[b * 32];
  // ensure xz[0] reads retired BEFORE advertising h(0) (slice-reuse proof)
  asm volatile("s_waitcnt vmcnt(0) lgkmcnt(0)" ::: "memory");

  // --- publish h(0): own units only, tag 1 ---
  for (int i = tid; i < 1024; i += 512) {
    int uu = U0 + (i >> 6), bb = i & 63;
    u32 cell = ((u32)f2bf(h0[(size_t)bb * HH + uu]) << 16) | 1u;
    __hip_atomic_store(&hinit[cellpos(bb, uu)], cell, __ATOMIC_RELAXED,
                       __HIP_MEMORY_SCOPE_AGENT);
  }

  const size_t OFS1 = (size_t)BB * TT * HH;
  const size_t OFS2 = OFS1 + (size_t)BB * HH;
  const u32* hb_prev = hinit;

  for (int t = 0; t < TT; ++t) {
    const u32 expect = (u32)(t + 1) & 0xffffu;
    // ---- stage h(t): 64 tagged cells per thread, lane-major coalesced ----
    u32 vals[64];
#pragma unroll
    for (int j = 0; j < 64; ++j)
      vals[j] = __hip_atomic_load(&hb_prev[j * 512 + tid], __ATOMIC_RELAXED,
                                  __HIP_MEMORY_SCOPE_AGENT);
    while (true) {
      u32 bad = 0;
#pragma unroll
      for (int j = 0; j < 64; ++j) bad |= (vals[j] ^ expect) & 0xffffu;
      if (bad == 0) break;
#pragma unroll
      for (int j = 0; j < 64; ++j)
        if (((vals[j] ^ expect) & 0xffffu) != 0)
          vals[j] = __hip_atomic_load(&hb_prev[j * 512 + tid],
                                      __ATOMIC_RELAXED,
                                      __HIP_MEMORY_SCOPE_AGENT);
      __builtin_amdgcn_s_sleep(1);
    }
    __syncthreads();  // bar1: all waves done reading previous A_lds
#pragma unroll
    for (int j = 0; j < 64; ++j)
      A_lds[j * 512 + tid] = (u16)(vals[j] >> 16);
    __syncthreads();  // bar2: A_lds ready

    // ---- A frags from LDS + MFMA ----
    bf16x8 af[16];
#pragma unroll
    for (int ks = 0; ks < 16; ++ks)
      af[ks] = *(const bf16x8*)&A_lds[((mt * 16 + ks) * 64 + l) * 8];
    f32x4 acc0 = {0.f, 0.f, 0.f, 0.f}, acc1 = {0.f, 0.f, 0.f, 0.f};
#pragma unroll
    for (int ks = 0; ks < 16; ++ks) {
      acc0 = __builtin_amdgcn_mfma_f32_16x16x32_bf16(af[ks], bfr0[ks], acc0,
                                                     0, 0, 0);
      acc1 = __builtin_amdgcn_mfma_f32_16x16x32_bf16(af[ks], bfr1[ks], acc1,
                                                     0, 0, 0);
    }

    const bool m = (mw >> (t & 31)) & 1;
    // next h-buffer: hbuf(t+1)
    u32* hb_next = (t == 0) ? ((u32*)xz) + 32768
                            : (u32*)(xz + (size_t)(t - 1) * GG * BB);
    const u32 ntag = (u32)(t + 2) & 0xffffu;
    float hosave[2], cosave[2];

    // ---- per tile: 4x4 lane-group transpose, gates, state update ----
#pragma unroll
    for (int ti = 0; ti < 2; ++ti) {
      f32x4 acc = ti ? acc1 : acc0;
      float accLo = (q & 1) ? acc[1] : acc[0];
      float accHi = (q & 1) ? acc[3] : acc[2];
      float sendA = (q & 1) ? acc[0] : acc[1];
      float recvA = __shfl_xor(sendA, 1);
      float sendB = (q & 1) ? acc[2] : acc[3];
      float recvB = __shfl_xor(sendB, 1);
      float k1 = (q & 2) ? accHi : accLo;
      float s2A = (q & 2) ? accLo : accHi;
      float r2A = __shfl_xor(s2A, 2);
      float k2 = (q & 2) ? recvB : recvA;
      float s2B = (q & 2) ? recvA : recvB;
      float r2B = __shfl_xor(s2B, 2);
      float p1 = (q & 1) ? k2 : k1;
      float p2 = (q & 1) ? k1 : k2;
      float p3 = (q & 1) ? r2B : r2A;
      float p4 = (q & 1) ? r2A : r2B;
      float W0 = (q & 2) ? p3 : p1;
      float W1 = (q & 2) ? p4 : p2;
      float W2 = (q & 2) ? p1 : p3;
      float W3 = (q & 2) ? p2 : p4;
      float z0 = W0 + xzc[ti ? 4 : 0];
      float z1 = W1 + xzc[ti ? 5 : 1];
      float z2 = W2 + xzc[ti ? 6 : 2];
      float z3 = W3 + xzc[ti ? 7 : 3];
      float ig = sigm(z0), fg = sigm(z1), gg = tanhfast(z2), og = sigm(z3);
      float cprev = ti ? creg1 : creg0;
      float hprev = ti ? hreg1 : hreg0;
      float cn = fg * cprev + ig * gg;
      float hn = og * tanhfast(cn);
      float ho = m ? hn : hprev;
      float co = m ? cn : cprev;
      if (ti) { creg1 = co; hreg1 = ho; } else { creg0 = co; hreg0 = ho; }
      hosave[ti] = ho; cosave[ti] = co;
      // publish immediately (shortens cross-WG critical path)
      if (t < TT - 1) {
        const int u = ti ? u1g : u0g;
        u32 cell = ((u32)f2bf(ho) << 16) | ntag;
        __hip_atomic_store(&hb_next[cellpos(b, u)], cell, __ATOMIC_RELAXED,
                           __HIP_MEMORY_SCOPE_AGENT);
      }
    }
    // ---- outputs (off critical path) ----
    out[((size_t)b * TT + t) * HH + u0g] = hosave[0];
    out[((size_t)b * TT + t) * HH + u1g] = hosave[1];
    if (t == TT - 1) {
      out[OFS1 + (size_t)b * HH + u0g] = hosave[0];
      out[OFS1 + (size_t)b * HH + u1g] = hosave[1];
      out[OFS2 + (size_t)b * HH + u0g] = cosave[0];
      out[OFS2 + (size_t)b * HH + u1g] = cosave[1];
    } else {
      // prefetch xz/mask for t+1 (values consumed before h(t+2) publish,
      // which is what the slice-reuse invariant needs)
      const int tn = t + 1;
#pragma unroll
      for (int g = 0; g < 4; ++g) {
        xzc[g]     = bf2f(xz[((size_t)tn * GG + g * HH + u0g) * BB + b]);
        xzc[4 + g] = bf2f(xz[((size_t)tn * GG + g * HH + u1g) * BB + b]);
      }
      if ((tn & 31) == 0) mw = xmask[b * 32 + (tn >> 5)];
    }
    hb_prev = hb_next;
  }
}

// ---------------------------------------------------------------------------
extern "C" void kernel_launch(void* const* d_in, const int* in_sizes, int n_in,
                              void* d_out, int out_size, void* d_ws,
                              size_t ws_size, hipStream_t stream) {
  const int* x = (const int*)d_in[0];
  const float* h0 = (const float*)d_in[1];
  const float* c0 = (const float*)d_in[2];
  const float* emb = (const float*)d_in[3];
  const float* Wk = (const float*)d_in[4];
  const float* rec = (const float*)d_in[5];
  const float* bias = (const float*)d_in[6];
  float* out = (float*)d_out;
  char* ws = (char*)d_ws;

  const size_t XZ_BYTES = (size_t)TT * GG * BB * 2;  // 256 MiB
  u16* xz = (u16*)ws;
  u32* hinit = (u32*)(ws + XZ_BYTES);  // 128 KiB (within proven slack)
  if (ws_size < XZ_BYTES + 139264) return;  // same floor round 1/2 proved

  hipFuncSetAttribute((const void*)xz_gemm_mfma,
                      hipFuncAttributeMaxDynamicSharedMemorySize, 131072);
  xz_gemm_mfma<<<TT, 256, 131072, stream>>>(x, emb, Wk, bias, xz);

  hipFuncSetAttribute((const void*)lstm_scan3,
                      hipFuncAttributeMaxDynamicSharedMemorySize, 73728);
  lstm_scan3<<<NWG, 512, 73728, stream>>>(x, h0, c0, rec, xz, out, hinit);
}

// Round 4
// 9340.726 us; speedup vs baseline: 1.6255x; 1.6255x over previous
//
#include <hip/hip_runtime.h>
#include <stdint.h>

typedef unsigned short u16;
typedef unsigned int u32;
typedef __attribute__((ext_vector_type(8))) short bf16x8;
typedef __attribute__((ext_vector_type(4))) float f32x4;
typedef __attribute__((ext_vector_type(4))) unsigned int u32x4;
typedef __attribute__((ext_vector_type(2))) unsigned int u32x2;

#define TT 1024
#define BB 64
#define EE 256
#define HH 512
#define GG 2048   // 4H
#define NWG 32    // scan workgroups, 16 h-units each

__device__ __forceinline__ float bf2f(u16 h) {
  union { u32 i; float f; } v; v.i = ((u32)h) << 16; return v.f;
}
__device__ __forceinline__ u16 f2bf(float f) {
  union { float f; u32 i; } v; v.f = f;
  u32 b = v.i;
  return (u16)((b + 0x7fffu + ((b >> 16) & 1u)) >> 16);
}
__device__ __forceinline__ float sigm(float x) {
  return 1.f / (1.f + __expf(-x));
}
__device__ __forceinline__ float tanhfast(float x) {
  float e = __expf(2.f * x);
  return 1.f - 2.f / (e + 1.f);
}
// tagged h-cell position (frag order): lane=(b&15)|(kOct<<4), j=u&7
__device__ __forceinline__ int cellpos(int b, int u) {
  return ((((b >> 4) * 16 + (u >> 5)) * 64) +
          ((b & 15) | (((u >> 3) & 3) << 4))) * 8 + (u & 7);
}

// ---------------------------------------------------------------------------
// Kernel 1: xz[t][col][b] bf16 = (emb[x[:,t]] @ kernel) + bias, via MFMA.
// (unchanged from round 3: ~0.4 ms, not the bottleneck)
// ---------------------------------------------------------------------------
__global__ __launch_bounds__(256) void xz_gemm_mfma(
    const int* __restrict__ x, const float* __restrict__ emb,
    const float* __restrict__ Wk, const float* __restrict__ bias,
    u16* __restrict__ xz) {
  extern __shared__ char sm1[];
  bf16x8* Bl = (bf16x8*)sm1;   // [8192] frags: (nt*8+ks)*64 + lane
  __shared__ int xidx[64];
  const int tid = threadIdx.x;
  const int t = blockIdx.x;
  const int w = tid >> 6, l = tid & 63;
  if (tid < 64) xidx[tid] = x[(size_t)tid * TT + t];
  __syncthreads();

  const int row = w * 16 + (l & 15);
  const int xid = xidx[row];
  bf16x8 af[8];
#pragma unroll
  for (int ks = 0; ks < 8; ++ks) {
    int k0 = ks * 32 + ((l >> 4) << 3);
    const float4* p = (const float4*)(emb + (size_t)xid * EE + k0);
    float4 a0 = p[0], a1 = p[1];
    bf16x8 v;
    v[0] = (short)f2bf(a0.x); v[1] = (short)f2bf(a0.y);
    v[2] = (short)f2bf(a0.z); v[3] = (short)f2bf(a0.w);
    v[4] = (short)f2bf(a1.x); v[5] = (short)f2bf(a1.y);
    v[6] = (short)f2bf(a1.z); v[7] = (short)f2bf(a1.w);
    af[ks] = v;
  }

  for (int nb = 0; nb < 8; ++nb) {
    __syncthreads();
    for (int idx = tid; idx < 8192; idx += 256) {
      int nt = idx >> 9, ks = (idx >> 6) & 7, l2 = idx & 63;
      int col = nb * 256 + nt * 16 + (l2 & 15);
      int kb = ks * 32 + ((l2 >> 4) << 3);
      bf16x8 v;
#pragma unroll
      for (int j = 0; j < 8; ++j)
        v[j] = (short)f2bf(Wk[(size_t)(kb + j) * GG + col]);
      Bl[idx] = v;
    }
    __syncthreads();
#pragma unroll 2
    for (int nt = 0; nt < 16; ++nt) {
      f32x4 acc = {0.f, 0.f, 0.f, 0.f};
#pragma unroll
      for (int ks = 0; ks < 8; ++ks)
        acc = __builtin_amdgcn_mfma_f32_16x16x32_bf16(
            af[ks], Bl[(nt * 8 + ks) * 64 + l], acc, 0, 0, 0);
      int col = nb * 256 + nt * 16 + (l & 15);
      float bj = bias[col];
      int b0 = w * 16 + ((l >> 4) << 2);
      u16 o0 = f2bf(acc[0] + bj), o1 = f2bf(acc[1] + bj);
      u16 o2 = f2bf(acc[2] + bj), o3 = f2bf(acc[3] + bj);
      u32* dst = (u32*)(xz + ((size_t)t * GG + col) * BB + b0);
      dst[0] = (u32)o0 | ((u32)o1 << 16);
      dst[1] = (u32)o2 | ((u32)o3 << 16);
    }
  }
}

// ---------------------------------------------------------------------------
// Kernel 2: persistent MFMA LSTM scan, tagged-word dataflow on FIXED hot
// buffers. h(t) lives in: hinit (t=0, tag 1) or xz slice (t-1)&1 (t>=1,
// tag t+1). Slices 0/1 are preloaded to regs + vmcnt-drained BEFORE h(0)
// publish; global stage(0) completion orders any slice overwrite after
// every WG's prefetch (invariant proven in round 3). Stage = 16x
// global_load_dwordx4 sc0 sc1 (per-dword atomic) + tag retry -> ping-pong
// LDS -> frags. One barrier per step.
// ---------------------------------------------------------------------------
__global__ __launch_bounds__(512, 2) void lstm_scan4(
    const int* __restrict__ x, const float* __restrict__ h0,
    const float* __restrict__ c0, const float* __restrict__ rec,
    u16* __restrict__ xz, float* __restrict__ out, u32* __restrict__ hinit) {
  extern __shared__ char sm2[];
  u16* A0 = (u16*)sm2;                 // [32768] cells
  u16* A1 = (u16*)(sm2 + 65536);       // [32768]
  u32* xmask = (u32*)(sm2 + 131072);   // [64][32]
  const int tid = threadIdx.x;
  const int wv = tid >> 6, l = tid & 63;
  const int w = blockIdx.x;
  const int U0 = w * 16;
  const int mt = wv & 3, ntp = wv >> 2;
  const int q = l & 3;
  const int b = mt * 16 + ((l >> 4) << 2) + q;
  const int uoff = (l >> 2) & 3;
  const int u0g = U0 + (2 * ntp + 0) * 4 + uoff;
  const int u1g = U0 + (2 * ntp + 1) * 4 + uoff;
  const int col0 = q * 512 + u0g;
  const int col1 = q * 512 + u1g;

  // --- B fragments (R slice) into registers, once ---
  bf16x8 bfr0[16], bfr1[16];
#pragma unroll
  for (int ks = 0; ks < 16; ++ks) {
    int kbase = ks * 32 + ((l >> 4) << 3);
#pragma unroll
    for (int j = 0; j < 8; ++j) {
      bfr0[ks][j] = (short)f2bf(rec[(size_t)(kbase + j) * GG + col0]);
      bfr1[ks][j] = (short)f2bf(rec[(size_t)(kbase + j) * GG + col1]);
    }
  }
  // --- x bitmask in LDS ---
  for (int i = tid; i < 2048; i += 512) {
    int bb = i >> 5, tw = i & 31;
    u32 mword = 0;
    for (int j = 0; j < 32; ++j)
      mword |= (x[(size_t)bb * TT + tw * 32 + j] != 0 ? 1u : 0u) << j;
    xmask[bb * 32 + tw] = mword;
  }
  float creg0 = c0[(size_t)b * HH + u0g];
  float creg1 = c0[(size_t)b * HH + u1g];
  float hreg0 = h0[(size_t)b * HH + u0g];
  float hreg1 = h0[(size_t)b * HH + u1g];
  __syncthreads();  // xmask ready

  // --- preload xz slices 0 and 1 (plain loads), drain, then publish h(0) ---
  float xzc[8], xzB[8];
#pragma unroll
  for (int g = 0; g < 4; ++g) {
    xzc[g]     = bf2f(xz[((size_t)0 * GG + g * HH + u0g) * BB + b]);
    xzc[4 + g] = bf2f(xz[((size_t)0 * GG + g * HH + u1g) * BB + b]);
    xzB[g]     = bf2f(xz[((size_t)1 * GG + g * HH + u0g) * BB + b]);
    xzB[4 + g] = bf2f(xz[((size_t)1 * GG + g * HH + u1g) * BB + b]);
  }
  u32 mw = xmask[b * 32];
  asm volatile("s_waitcnt vmcnt(0) lgkmcnt(0)" ::: "memory");

  for (int i = tid; i < 1024; i += 512) {
    int uu = U0 + (i >> 6), bb = i & 63;
    u32 cell = ((u32)f2bf(h0[(size_t)bb * HH + uu]) << 16) | 1u;
    __hip_atomic_store(&hinit[cellpos(bb, uu)], cell, __ATOMIC_RELAXED,
                       __HIP_MEMORY_SCOPE_AGENT);
  }

  const size_t OFS1 = (size_t)BB * TT * HH;
  const size_t OFS2 = OFS1 + (size_t)BB * HH;
  const u32* hb_prev = hinit;

  for (int t = 0; t < TT; ++t) {
    const u32 expect = (u32)(t + 1) & 0xffffu;
    // ---- stage h(t): 16 x4 loads (sc0 sc1 = L1/L2-bypass, MALL-fresh) ----
    u32x4 v[16];
#pragma unroll
    for (int r = 0; r < 16; ++r)
      asm volatile("global_load_dwordx4 %0, %1, off sc0 sc1"
                   : "=v"(v[r]) : "v"(hb_prev + r * 2048 + tid * 4));
    asm volatile("s_waitcnt vmcnt(0)" ::: "memory");
    __builtin_amdgcn_sched_barrier(0);
    while (true) {
      u32 sm = 0;
#pragma unroll
      for (int r = 0; r < 16; ++r) {
        u32 bad = ((v[r][0] ^ expect) | (v[r][1] ^ expect) |
                   (v[r][2] ^ expect) | (v[r][3] ^ expect)) & 0xffffu;
        sm |= (bad ? 1u : 0u) << r;
      }
      if (!__any(sm != 0)) break;
      __builtin_amdgcn_s_sleep(1);
#pragma unroll
      for (int r = 0; r < 16; ++r)
        if (__any((sm >> r) & 1u))
          asm volatile("global_load_dwordx4 %0, %1, off sc0 sc1"
                       : "=v"(v[r]) : "v"(hb_prev + r * 2048 + tid * 4));
      asm volatile("s_waitcnt vmcnt(0)" ::: "memory");
      __builtin_amdgcn_sched_barrier(0);
    }
    // ---- strip tags -> ping-pong LDS ----
    u16* Ac = (t & 1) ? A1 : A0;
#pragma unroll
    for (int r = 0; r < 16; ++r) {
      u32 d0 = (v[r][0] >> 16) | (v[r][1] & 0xffff0000u);
      u32 d1 = (v[r][2] >> 16) | (v[r][3] & 0xffff0000u);
      u32x2 dd; dd[0] = d0; dd[1] = d1;
      *(u32x2*)&Ac[r * 2048 + tid * 4] = dd;
    }
    __syncthreads();  // A ready (single barrier per step; ping-pong safe)

    // ---- A frags from LDS + MFMA ----
    bf16x8 af[16];
#pragma unroll
    for (int ks = 0; ks < 16; ++ks)
      af[ks] = *(const bf16x8*)&Ac[((mt * 16 + ks) * 64 + l) * 8];
    f32x4 acc0 = {0.f, 0.f, 0.f, 0.f}, acc1 = {0.f, 0.f, 0.f, 0.f};
#pragma unroll
    for (int ks = 0; ks < 16; ++ks) {
      acc0 = __builtin_amdgcn_mfma_f32_16x16x32_bf16(af[ks], bfr0[ks], acc0,
                                                     0, 0, 0);
      acc1 = __builtin_amdgcn_mfma_f32_16x16x32_bf16(af[ks], bfr1[ks], acc1,
                                                     0, 0, 0);
    }

    const bool m = (mw >> (t & 31)) & 1;
    // hb(t+1) = xz slice (t&1) first half (fixed hot buffers)
    u32* hb_next = (u32*)xz + (size_t)(t & 1) * 65536;
    const u32 ntag = (u32)(t + 2) & 0xffffu;
    float hosave[2], cosave[2];

#pragma unroll
    for (int ti = 0; ti < 2; ++ti) {
      f32x4 acc = ti ? acc1 : acc0;
      float accLo = (q & 1) ? acc[1] : acc[0];
      float accHi = (q & 1) ? acc[3] : acc[2];
      float sendA = (q & 1) ? acc[0] : acc[1];
      float recvA = __shfl_xor(sendA, 1);
      float sendB = (q & 1) ? acc[2] : acc[3];
      float recvB = __shfl_xor(sendB, 1);
      float k1 = (q & 2) ? accHi : accLo;
      float s2A = (q & 2) ? accLo : accHi;
      float r2A = __shfl_xor(s2A, 2);
      float k2 = (q & 2) ? recvB : recvA;
      float s2B = (q & 2) ? recvA : recvB;
      float r2B = __shfl_xor(s2B, 2);
      float p1 = (q & 1) ? k2 : k1;
      float p2 = (q & 1) ? k1 : k2;
      float p3 = (q & 1) ? r2B : r2A;
      float p4 = (q & 1) ? r2A : r2B;
      float W0 = (q & 2) ? p3 : p1;
      float W1 = (q & 2) ? p4 : p2;
      float W2 = (q & 2) ? p1 : p3;
      float W3 = (q & 2) ? p2 : p4;
      float z0 = W0 + xzc[ti ? 4 : 0];
      float z1 = W1 + xzc[ti ? 5 : 1];
      float z2 = W2 + xzc[ti ? 6 : 2];
      float z3 = W3 + xzc[ti ? 7 : 3];
      float ig = sigm(z0), fg = sigm(z1), gg = tanhfast(z2), og = sigm(z3);
      float cprev = ti ? creg1 : creg0;
      float hprev = ti ? hreg1 : hreg0;
      float cn = fg * cprev + ig * gg;
      float hn = og * tanhfast(cn);
      float ho = m ? hn : hprev;
      float co = m ? cn : cprev;
      if (ti) { creg1 = co; hreg1 = ho; } else { creg0 = co; hreg0 = ho; }
      hosave[ti] = ho; cosave[ti] = co;
      if (t < TT - 1) {
        const int u = ti ? u1g : u0g;
        u32 cell = ((u32)f2bf(ho) << 16) | ntag;
        __hip_atomic_store(&hb_next[cellpos(b, u)], cell, __ATOMIC_RELAXED,
                           __HIP_MEMORY_SCOPE_AGENT);
      }
    }
    // ---- outputs + next xz prefetch (off critical path) ----
    __builtin_nontemporal_store(hosave[0], &out[((size_t)b * TT + t) * HH + u0g]);
    __builtin_nontemporal_store(hosave[1], &out[((size_t)b * TT + t) * HH + u1g]);
    if (t == TT - 1) {
      out[OFS1 + (size_t)b * HH + u0g] = hosave[0];
      out[OFS1 + (size_t)b * HH + u1g] = hosave[1];
      out[OFS2 + (size_t)b * HH + u0g] = cosave[0];
      out[OFS2 + (size_t)b * HH + u1g] = cosave[1];
    } else {
      const int tn = t + 1;
      if ((tn & 31) == 0) mw = xmask[b * 32 + (tn >> 5)];
      if (tn == 1) {
#pragma unroll
        for (int g = 0; g < 8; ++g) xzc[g] = xzB[g];
      } else {
#pragma unroll
        for (int g = 0; g < 4; ++g) {
          xzc[g]     = bf2f(xz[((size_t)tn * GG + g * HH + u0g) * BB + b]);
          xzc[4 + g] = bf2f(xz[((size_t)tn * GG + g * HH + u1g) * BB + b]);
        }
      }
    }
    hb_prev = hb_next;
  }
}

// ---------------------------------------------------------------------------
extern "C" void kernel_launch(void* const* d_in, const int* in_sizes, int n_in,
                              void* d_out, int out_size, void* d_ws,
                              size_t ws_size, hipStream_t stream) {
  const int* x = (const int*)d_in[0];
  const float* h0 = (const float*)d_in[1];
  const float* c0 = (const float*)d_in[2];
  const float* emb = (const float*)d_in[3];
  const float* Wk = (const float*)d_in[4];
  const float* rec = (const float*)d_in[5];
  const float* bias = (const float*)d_in[6];
  float* out = (float*)d_out;
  char* ws = (char*)d_ws;

  const size_t XZ_BYTES = (size_t)TT * GG * BB * 2;  // 256 MiB
  u16* xz = (u16*)ws;
  u32* hinit = (u32*)(ws + XZ_BYTES);  // 128 KiB (ws floor proven r1-r3)
  if (ws_size < XZ_BYTES + 131072) return;

  hipFuncSetAttribute((const void*)xz_gemm_mfma,
                      hipFuncAttributeMaxDynamicSharedMemorySize, 131072);
  xz_gemm_mfma<<<TT, 256, 131072, stream>>>(x, emb, Wk, bias, xz);

  hipFuncSetAttribute((const void*)lstm_scan4,
                      hipFuncAttributeMaxDynamicSharedMemorySize, 139264);
  lstm_scan4<<<NWG, 512, 139264, stream>>>(x, h0, c0, rec, xz, out, hinit);
}

// Round 5
// 4462.399 us; speedup vs baseline: 3.4025x; 2.0932x over previous
//
#include <hip/hip_runtime.h>
#include <stdint.h>

typedef unsigned short u16;
typedef unsigned int u32;
typedef __attribute__((ext_vector_type(8))) short bf16x8;
typedef __attribute__((ext_vector_type(4))) float f32x4;
typedef __attribute__((ext_vector_type(4))) unsigned int u32x4;
typedef __attribute__((ext_vector_type(2))) unsigned int u32x2;

#define TT 1024
#define BB 64
#define EE 256
#define HH 512
#define GG 2048   // 4H
#define NWG 32    // 4 groups x 8 WGs

#define AS1 __attribute__((address_space(1)))
#define AS3 __attribute__((address_space(3)))

__device__ __forceinline__ float bf2f(u16 h) {
  union { u32 i; float f; } v; v.i = ((u32)h) << 16; return v.f;
}
__device__ __forceinline__ u16 f2bf(float f) {
  union { float f; u32 i; } v; v.f = f;
  u32 b = v.i;
  return (u16)((b + 0x7fffu + ((b >> 16) & 1u)) >> 16);
}
__device__ __forceinline__ float sigm(float x) {
  return 1.f / (1.f + __expf(-x));
}
__device__ __forceinline__ float tanhfast(float x) {
  float e = __expf(2.f * x);
  return 1.f - 2.f / (e + 1.f);
}
// cell position within a group h-buffer (8192 cells): A-frag order for 16x16
__device__ __forceinline__ int cellpos16(int bl, int u) {
  return (((u >> 5) * 64) + ((bl & 15) | (((u >> 3) & 3) << 4))) * 8 + (u & 7);
}

// ---------------------------------------------------------------------------
// Kernel 1: xz[t][col][b] bf16 = (emb[x[:,t]] @ kernel) + bias, via MFMA.
// (unchanged from round 3/4, ~0.4 ms)
// ---------------------------------------------------------------------------
__global__ __launch_bounds__(256) void xz_gemm_mfma(
    const int* __restrict__ x, const float* __restrict__ emb,
    const float* __restrict__ Wk, const float* __restrict__ bias,
    u16* __restrict__ xz) {
  extern __shared__ char sm1[];
  bf16x8* Bl = (bf16x8*)sm1;   // [8192] frags: (nt*8+ks)*64 + lane
  __shared__ int xidx[64];
  const int tid = threadIdx.x;
  const int t = blockIdx.x;
  const int w = tid >> 6, l = tid & 63;
  if (tid < 64) xidx[tid] = x[(size_t)tid * TT + t];
  __syncthreads();

  const int row = w * 16 + (l & 15);
  const int xid = xidx[row];
  bf16x8 af[8];
#pragma unroll
  for (int ks = 0; ks < 8; ++ks) {
    int k0 = ks * 32 + ((l >> 4) << 3);
    const float4* p = (const float4*)(emb + (size_t)xid * EE + k0);
    float4 a0 = p[0], a1 = p[1];
    bf16x8 v;
    v[0] = (short)f2bf(a0.x); v[1] = (short)f2bf(a0.y);
    v[2] = (short)f2bf(a0.z); v[3] = (short)f2bf(a0.w);
    v[4] = (short)f2bf(a1.x); v[5] = (short)f2bf(a1.y);
    v[6] = (short)f2bf(a1.z); v[7] = (short)f2bf(a1.w);
    af[ks] = v;
  }

  for (int nb = 0; nb < 8; ++nb) {
    __syncthreads();
    for (int idx = tid; idx < 8192; idx += 256) {
      int nt = idx >> 9, ks = (idx >> 6) & 7, l2 = idx & 63;
      int col = nb * 256 + nt * 16 + (l2 & 15);
      int kb = ks * 32 + ((l2 >> 4) << 3);
      bf16x8 v;
#pragma unroll
      for (int j = 0; j < 8; ++j)
        v[j] = (short)f2bf(Wk[(size_t)(kb + j) * GG + col]);
      Bl[idx] = v;
    }
    __syncthreads();
#pragma unroll 2
    for (int nt = 0; nt < 16; ++nt) {
      f32x4 acc = {0.f, 0.f, 0.f, 0.f};
#pragma unroll
      for (int ks = 0; ks < 8; ++ks)
        acc = __builtin_amdgcn_mfma_f32_16x16x32_bf16(
            af[ks], Bl[(nt * 8 + ks) * 64 + l], acc, 0, 0, 0);
      int col = nb * 256 + nt * 16 + (l & 15);
      float bj = bias[col];
      int b0 = w * 16 + ((l >> 4) << 2);
      u16 o0 = f2bf(acc[0] + bj), o1 = f2bf(acc[1] + bj);
      u16 o2 = f2bf(acc[2] + bj), o3 = f2bf(acc[3] + bj);
      u32* dst = (u32*)(xz + ((size_t)t * GG + col) * BB + b0);
      dst[0] = (u32)o0 | ((u32)o1 << 16);
      dst[1] = (u32)o2 | ((u32)o3 << 16);
    }
  }
}

// ---------------------------------------------------------------------------
// Kernel 2: persistent MFMA LSTM scan, GROUPED tagged-word dataflow.
// 4 independent groups x 8 WGs. Group g owns batches [16g,16g+16); WG r in
// group owns units [64r,64r+64) (256 gate-cols). Per-group h exchange:
// 8192 tagged u32 cells (16b x 512u), double-buffered:
//   parity0 = hinit + g*8192 (dedicated ws), parity1 = out hT region
//   (overwritten with real hT after a once-only end handshake).
// h(t) lives in parity t&1 tagged t+1. Stage = 4x dwordx4 sc0 sc1 + retry.
// xz flows through per-wave LDS ring slabs via global_load_lds (8 deep).
// ---------------------------------------------------------------------------
__global__ __launch_bounds__(512, 2) void lstm_scan5(
    const int* __restrict__ x, const float* __restrict__ h0,
    const float* __restrict__ c0, const float* __restrict__ rec,
    const u16* __restrict__ xz, float* __restrict__ out,
    u32* __restrict__ hinit, u32* __restrict__ flags) {
  extern __shared__ char sm2[];
  u16* A0 = (u16*)sm2;                // 16 KB (8192 bf16 cells)
  u16* A1 = (u16*)(sm2 + 16384);      // 16 KB
  u32* xmask = (u32*)(sm2 + 32768);   // 2 KB [16][32]
  char* ring = sm2 + 34816;           // 8 slots * 8 waves * 1KB = 64 KB
  const int tid = threadIdx.x;
  const int wv = tid >> 6, l = tid & 63;
  const int g = blockIdx.x >> 3;      // group
  const int r = blockIdx.x & 7;       // WG within group
  const int Bg = g * 16;
  const int U0 = r * 64;
  const int q = l & 3;
  const int bl = ((l >> 4) << 2) + q;     // local batch 0..15
  const int b = Bg + bl;
  const int uoff = (l >> 2) & 3;
  const int u0g = U0 + 8 * wv + uoff;
  const int u1g = U0 + 8 * wv + 4 + uoff;
  const int col0 = q * 512 + u0g;
  const int col1 = q * 512 + u1g;

  // ring slab lane addressing: lane covers (gate=cg>>3, uo=cg&7, half=l&1)
  const int cg = l >> 1;
  const int colL = (cg >> 3) * 512 + U0 + 8 * wv + (cg & 7);
  const size_t gofsL = (size_t)colL * BB + Bg + ((l & 1) << 3);
  char* myslabs = ring + (wv << 10);  // + slot*8192

  // prime xz slabs t=0..6 (issued first: overlaps the heavy B-frag staging)
#pragma unroll
  for (int s = 0; s < 7; ++s) {
    const u16* gp = xz + (size_t)s * GG * BB + gofsL;
    __builtin_amdgcn_global_load_lds((AS1 const u32*)gp,
                                     (AS3 u32*)(myslabs + s * 8192), 16, 0, 0);
  }

  // --- B fragments (R slice) into registers, once ---
  bf16x8 bfr0[16], bfr1[16];
#pragma unroll
  for (int ks = 0; ks < 16; ++ks) {
    int kbase = ks * 32 + ((l >> 4) << 3);
#pragma unroll
    for (int j = 0; j < 8; ++j) {
      bfr0[ks][j] = (short)f2bf(rec[(size_t)(kbase + j) * GG + col0]);
      bfr1[ks][j] = (short)f2bf(rec[(size_t)(kbase + j) * GG + col1]);
    }
  }
  // --- x bitmask for group's 16 batches ---
  {
    int bb = tid >> 5, tw = tid & 31;   // 512 threads = 16*32 exactly
    u32 mword = 0;
    for (int j = 0; j < 32; ++j)
      mword |= (x[(size_t)(Bg + bb) * TT + tw * 32 + j] != 0 ? 1u : 0u) << j;
    xmask[bb * 32 + tw] = mword;
  }
  float creg0 = c0[(size_t)b * HH + u0g];
  float creg1 = c0[(size_t)b * HH + u1g];
  float hreg0 = h0[(size_t)b * HH + u0g];
  float hreg1 = h0[(size_t)b * HH + u1g];
  __syncthreads();  // xmask ready

  const size_t OFS1 = (size_t)BB * TT * HH;
  const size_t OFS2 = OFS1 + (size_t)BB * HH;
  u32* P0 = hinit + g * 8192;
  u32* P1 = (u32*)out + OFS1 + (size_t)g * 8192;  // hT region (zeroed/launch)

  // --- publish h(0) into P0, tag 1 (each WG publishes its 64 units) ---
#pragma unroll
  for (int i = 0; i < 2; ++i) {
    int idx = tid + i * 512;            // 1024 cells
    int uu = U0 + (idx >> 4), bl2 = idx & 15;
    u32 cell = ((u32)f2bf(h0[(size_t)(Bg + bl2) * HH + uu]) << 16) | 1u;
    __hip_atomic_store(&P0[cellpos16(bl2, uu)], cell, __ATOMIC_RELAXED,
                       __HIP_MEMORY_SCOPE_AGENT);
  }

  u32 mw = 0;
  for (int t = 0; t < TT; ++t) {
    const u32 expect = (u32)(t + 1);
    const u32* hb_prev = (t & 1) ? P1 : P0;
    // ---- stage h(t): 4 x dwordx4 (sc0 sc1) + tag retry ----
    u32x4 v4[4];
#pragma unroll
    for (int rr = 0; rr < 4; ++rr)
      asm volatile("global_load_dwordx4 %0, %1, off sc0 sc1"
                   : "=v"(v4[rr]) : "v"(hb_prev + rr * 2048 + tid * 4));
    asm volatile("s_waitcnt vmcnt(0)" ::: "memory");
    __builtin_amdgcn_sched_barrier(0);
    while (true) {
      u32 sm = 0;
#pragma unroll
      for (int rr = 0; rr < 4; ++rr) {
        u32 bad = ((v4[rr][0] ^ expect) | (v4[rr][1] ^ expect) |
                   (v4[rr][2] ^ expect) | (v4[rr][3] ^ expect)) & 0xffffu;
        sm |= (bad ? 1u : 0u) << rr;
      }
      if (!__any(sm != 0)) break;
      __builtin_amdgcn_s_sleep(1);
#pragma unroll
      for (int rr = 0; rr < 4; ++rr)
        if (__any((sm >> rr) & 1u))
          asm volatile("global_load_dwordx4 %0, %1, off sc0 sc1"
                       : "=v"(v4[rr]) : "v"(hb_prev + rr * 2048 + tid * 4));
      asm volatile("s_waitcnt vmcnt(0)" ::: "memory");
      __builtin_amdgcn_sched_barrier(0);
    }
    // ---- strip tags -> ping-pong A ----
    u16* Ac = (t & 1) ? A1 : A0;
#pragma unroll
    for (int rr = 0; rr < 4; ++rr) {
      u32x2 dd;
      dd[0] = (v4[rr][0] >> 16) | (v4[rr][1] & 0xffff0000u);
      dd[1] = (v4[rr][2] >> 16) | (v4[rr][3] & 0xffff0000u);
      *(u32x2*)&Ac[rr * 2048 + tid * 4] = dd;
    }
    asm volatile("s_waitcnt lgkmcnt(0)" ::: "memory");
    __builtin_amdgcn_s_barrier();       // raw barrier: no vmcnt drain
    __builtin_amdgcn_sched_barrier(0);

    // ---- issue xz slab for t+7 (fire-and-forget, ages a full step) ----
    if (t + 7 < TT) {
      const u16* gp = xz + (size_t)(t + 7) * GG * BB + gofsL;
      __builtin_amdgcn_global_load_lds(
          (AS1 const u32*)gp, (AS3 u32*)(myslabs + ((t + 7) & 7) * 8192),
          16, 0, 0);
    }

    // ---- A frags + MFMA ----
    bf16x8 af[16];
#pragma unroll
    for (int ks = 0; ks < 16; ++ks)
      af[ks] = *(const bf16x8*)&Ac[(ks * 64 + l) * 8];
    f32x4 acc0 = {0.f, 0.f, 0.f, 0.f}, acc1 = {0.f, 0.f, 0.f, 0.f};
#pragma unroll
    for (int ks = 0; ks < 16; ++ks) {
      acc0 = __builtin_amdgcn_mfma_f32_16x16x32_bf16(af[ks], bfr0[ks], acc0,
                                                     0, 0, 0);
      acc1 = __builtin_amdgcn_mfma_f32_16x16x32_bf16(af[ks], bfr1[ks], acc1,
                                                     0, 0, 0);
    }

    if ((t & 31) == 0) mw = xmask[bl * 32 + (t >> 5)];
    const bool m = (mw >> (t & 31)) & 1;
    // ---- xz for this step from LDS ring slab ----
    const char* slab = ring + (((t & 7) * 8 + wv) << 10);
    float xzv[8];
#pragma unroll
    for (int g2 = 0; g2 < 4; ++g2) {
      xzv[g2] = bf2f(*(const u16*)(
          slab + (((g2 * 8 + uoff) * 2 + (bl >> 3)) << 4) + ((bl & 7) << 1)));
      xzv[4 + g2] = bf2f(*(const u16*)(
          slab + (((g2 * 8 + 4 + uoff) * 2 + (bl >> 3)) << 4) +
          ((bl & 7) << 1)));
    }

    u32* hb_next = (t & 1) ? P0 : P1;
    const u32 ntag = (u32)(t + 2);
    float hosave[2], cosave[2];

    // ---- per tile: 4x4 lane-group transpose, gates, state update ----
#pragma unroll
    for (int ti = 0; ti < 2; ++ti) {
      f32x4 acc = ti ? acc1 : acc0;
      float accLo = (q & 1) ? acc[1] : acc[0];
      float accHi = (q & 1) ? acc[3] : acc[2];
      float sendA = (q & 1) ? acc[0] : acc[1];
      float recvA = __shfl_xor(sendA, 1);
      float sendB = (q & 1) ? acc[2] : acc[3];
      float recvB = __shfl_xor(sendB, 1);
      float k1 = (q & 2) ? accHi : accLo;
      float s2A = (q & 2) ? accLo : accHi;
      float r2A = __shfl_xor(s2A, 2);
      float k2 = (q & 2) ? recvB : recvA;
      float s2B = (q & 2) ? recvA : recvB;
      float r2B = __shfl_xor(s2B, 2);
      float p1 = (q & 1) ? k2 : k1;
      float p2 = (q & 1) ? k1 : k2;
      float p3 = (q & 1) ? r2B : r2A;
      float p4 = (q & 1) ? r2A : r2B;
      float W0 = (q & 2) ? p3 : p1;
      float W1 = (q & 2) ? p4 : p2;
      float W2 = (q & 2) ? p1 : p3;
      float W3 = (q & 2) ? p2 : p4;
      float z0 = W0 + xzv[ti ? 4 : 0];
      float z1 = W1 + xzv[ti ? 5 : 1];
      float z2 = W2 + xzv[ti ? 6 : 2];
      float z3 = W3 + xzv[ti ? 7 : 3];
      float ig = sigm(z0), fg = sigm(z1), gg = tanhfast(z2), og = sigm(z3);
      float cprev = ti ? creg1 : creg0;
      float hprev = ti ? hreg1 : hreg0;
      float cn = fg * cprev + ig * gg;
      float hn = og * tanhfast(cn);
      float ho = m ? hn : hprev;
      float co = m ? cn : cprev;
      if (ti) { creg1 = co; hreg1 = ho; } else { creg0 = co; hreg0 = ho; }
      hosave[ti] = ho; cosave[ti] = co;
      if (t < TT - 1) {
        const int u = ti ? u1g : u0g;
        u32 cell = ((u32)f2bf(ho) << 16) | ntag;
        __hip_atomic_store(&hb_next[cellpos16(bl, u)], cell, __ATOMIC_RELAXED,
                           __HIP_MEMORY_SCOPE_AGENT);
      }
    }
    // ---- outputs (off critical path) ----
    __builtin_nontemporal_store(hosave[0],
                                &out[((size_t)b * TT + t) * HH + u0g]);
    __builtin_nontemporal_store(hosave[1],
                                &out[((size_t)b * TT + t) * HH + u1g]);
    if (t == TT - 1) {
      // cT region was never a buffer: write immediately
      out[OFS2 + (size_t)b * HH + u0g] = cosave[0];
      out[OFS2 + (size_t)b * HH + u1g] = cosave[1];
      // group handshake: every WG finished staging parity1 (hT region).
      // (this WG's stage(TT-1) completed before the s_barrier above)
      if (tid == 0)
        __hip_atomic_store(&flags[(g * 8 + r) * 16], 1u, __ATOMIC_RELEASE,
                           __HIP_MEMORY_SCOPE_AGENT);
      while (true) {
        u32 f = 1u;
        if (l < 8)
          f = __hip_atomic_load(&flags[(g * 8 + l) * 16], __ATOMIC_ACQUIRE,
                                __HIP_MEMORY_SCOPE_AGENT);
        if (__all(f >= 1u)) break;
        __builtin_amdgcn_s_sleep(2);
      }
      out[OFS1 + (size_t)b * HH + u0g] = hosave[0];
      out[OFS1 + (size_t)b * HH + u1g] = hosave[1];
    }
  }
}

// ---------------------------------------------------------------------------
extern "C" void kernel_launch(void* const* d_in, const int* in_sizes, int n_in,
                              void* d_out, int out_size, void* d_ws,
                              size_t ws_size, hipStream_t stream) {
  const int* x = (const int*)d_in[0];
  const float* h0 = (const float*)d_in[1];
  const float* c0 = (const float*)d_in[2];
  const float* emb = (const float*)d_in[3];
  const float* Wk = (const float*)d_in[4];
  const float* rec = (const float*)d_in[5];
  const float* bias = (const float*)d_in[6];
  float* out = (float*)d_out;
  char* ws = (char*)d_ws;

  const size_t XZ_BYTES = (size_t)TT * GG * BB * 2;  // 256 MiB
  u16* xz = (u16*)ws;
  u32* hinit = (u32*)(ws + XZ_BYTES);            // 128 KiB parity0 buffers
  u32* flags = (u32*)(ws + XZ_BYTES + 131072);   // 2 KiB handshake flags
  if (ws_size < XZ_BYTES + 133120) return;       // within proven r3 floor

  const size_t OFS1 = (size_t)BB * TT * HH;
  hipMemsetAsync(hinit, 0, 131072, stream);
  hipMemsetAsync(flags, 0, 2048, stream);
  // zero parity1 (hT region of out): kills stale-tag false matches
  hipMemsetAsync((char*)d_out + OFS1 * 4, 0, 131072, stream);

  hipFuncSetAttribute((const void*)xz_gemm_mfma,
                      hipFuncAttributeMaxDynamicSharedMemorySize, 131072);
  xz_gemm_mfma<<<TT, 256, 131072, stream>>>(x, emb, Wk, bias, xz);

  hipFuncSetAttribute((const void*)lstm_scan5,
                      hipFuncAttributeMaxDynamicSharedMemorySize, 100352);
  lstm_scan5<<<NWG, 512, 100352, stream>>>(x, h0, c0, rec, xz, out, hinit,
                                           flags);
}

// Round 6
// 3191.861 us; speedup vs baseline: 4.7568x; 1.3981x over previous
//
#include <hip/hip_runtime.h>
#include <stdint.h>

typedef unsigned short u16;
typedef unsigned int u32;
typedef __attribute__((ext_vector_type(8))) short bf16x8;
typedef __attribute__((ext_vector_type(4))) float f32x4;
typedef __attribute__((ext_vector_type(4))) unsigned int u32x4;
typedef __attribute__((ext_vector_type(2))) unsigned int u32x2;

#define TT 1024
#define BB 64
#define EE 256
#define HH 512
#define GG 2048   // 4H

#define AS1 __attribute__((address_space(1)))
#define AS3 __attribute__((address_space(3)))

__device__ __forceinline__ float bf2f(u16 h) {
  union { u32 i; float f; } v; v.i = ((u32)h) << 16; return v.f;
}
__device__ __forceinline__ u16 f2bf(float f) {
  union { float f; u32 i; } v; v.f = f;
  u32 b = v.i;
  return (u16)((b + 0x7fffu + ((b >> 16) & 1u)) >> 16);
}
__device__ __forceinline__ float sigm(float x) {
  return 1.f / (1.f + __expf(-x));
}
__device__ __forceinline__ float tanhfast(float x) {
  float e = __expf(2.f * x);
  return 1.f - 2.f / (e + 1.f);
}
// r5 cell position (16-batch groups)
__device__ __forceinline__ int cellpos16(int bl, int u) {
  return (((u >> 5) * 64) + ((bl & 15) | (((u >> 3) & 3) << 4))) * 8 + (u & 7);
}
// r6 cell position (8-batch groups): word idx in 4096-cell buffer
__device__ __forceinline__ int cellpos8(int bl, int u) {
  return ((u >> 5) * 32 + ((bl & 7) | (((u >> 3) & 3) << 3))) * 8 + (u & 7);
}
__device__ __forceinline__ int rowbad(u32x4 v, u32 e) {
  return ((((v[0] ^ e) | (v[1] ^ e)) | ((v[2] ^ e) | (v[3] ^ e))) & 0xffffu)
         != 0;
}

#define LOADF(dst, ptr)                                              \
  asm volatile("global_load_dwordx4 %0, %1, off sc0"                 \
               : "=v"(dst) : "v"(ptr))
#define LOADS(dst, ptr)                                              \
  asm volatile("global_load_dwordx4 %0, %1, off sc0 sc1"             \
               : "=v"(dst) : "v"(ptr))
#define WAITV0                                                       \
  asm volatile("s_waitcnt vmcnt(0)" ::: "memory");                   \
  __builtin_amdgcn_sched_barrier(0)

// ---------------------------------------------------------------------------
// Kernel 1: xz[t][col][b] bf16 = (emb[x[:,t]] @ kernel) + bias, via MFMA.
// (unchanged from rounds 3-5, ~0.45 ms)
// ---------------------------------------------------------------------------
__global__ __launch_bounds__(256) void xz_gemm_mfma(
    const int* __restrict__ x, const float* __restrict__ emb,
    const float* __restrict__ Wk, const float* __restrict__ bias,
    u16* __restrict__ xz) {
  extern __shared__ char sm1[];
  bf16x8* Bl = (bf16x8*)sm1;
  __shared__ int xidx[64];
  const int tid = threadIdx.x;
  const int t = blockIdx.x;
  const int w = tid >> 6, l = tid & 63;
  if (tid < 64) xidx[tid] = x[(size_t)tid * TT + t];
  __syncthreads();

  const int row = w * 16 + (l & 15);
  const int xid = xidx[row];
  bf16x8 af[8];
#pragma unroll
  for (int ks = 0; ks < 8; ++ks) {
    int k0 = ks * 32 + ((l >> 4) << 3);
    const float4* p = (const float4*)(emb + (size_t)xid * EE + k0);
    float4 a0 = p[0], a1 = p[1];
    bf16x8 v;
    v[0] = (short)f2bf(a0.x); v[1] = (short)f2bf(a0.y);
    v[2] = (short)f2bf(a0.z); v[3] = (short)f2bf(a0.w);
    v[4] = (short)f2bf(a1.x); v[5] = (short)f2bf(a1.y);
    v[6] = (short)f2bf(a1.z); v[7] = (short)f2bf(a1.w);
    af[ks] = v;
  }

  for (int nb = 0; nb < 8; ++nb) {
    __syncthreads();
    for (int idx = tid; idx < 8192; idx += 256) {
      int nt = idx >> 9, ks = (idx >> 6) & 7, l2 = idx & 63;
      int col = nb * 256 + nt * 16 + (l2 & 15);
      int kb = ks * 32 + ((l2 >> 4) << 3);
      bf16x8 v;
#pragma unroll
      for (int j = 0; j < 8; ++j)
        v[j] = (short)f2bf(Wk[(size_t)(kb + j) * GG + col]);
      Bl[idx] = v;
    }
    __syncthreads();
#pragma unroll 2
    for (int nt = 0; nt < 16; ++nt) {
      f32x4 acc = {0.f, 0.f, 0.f, 0.f};
#pragma unroll
      for (int ks = 0; ks < 8; ++ks)
        acc = __builtin_amdgcn_mfma_f32_16x16x32_bf16(
            af[ks], Bl[(nt * 8 + ks) * 64 + l], acc, 0, 0, 0);
      int col = nb * 256 + nt * 16 + (l & 15);
      float bj = bias[col];
      int b0 = w * 16 + ((l >> 4) << 2);
      u16 o0 = f2bf(acc[0] + bj), o1 = f2bf(acc[1] + bj);
      u16 o2 = f2bf(acc[2] + bj), o3 = f2bf(acc[3] + bj);
      u32* dst = (u32*)(xz + ((size_t)t * GG + col) * BB + b0);
      dst[0] = (u32)o0 | ((u32)o1 << 16);
      dst[1] = (u32)o2 | ((u32)o3 << 16);
    }
  }
}

// ---------------------------------------------------------------------------
// Kernel 2 (round 6): XCD-local grouped scan. 64 WGs x 512 thr.
// group g = bid&7 (-> XCD g under round-robin), member r = bid>>3.
// Group g owns batches [8g,8g+8); WG owns units [64r,64r+64).
// Exchange: 4096 tagged u32 cells per (group,parity); DUAL copies:
//   fast = plain store -> home-XCD L2, polled with sc0
//   slow = sc1 MALL copy (r5-proven protocol) as fallback/merge source.
// h(tau) -> parity tau&1, tag tau+1. M=8 MFMA (rows 8-15 duplicated, unused).
// ---------------------------------------------------------------------------
__global__ __launch_bounds__(512, 2) void lstm_scan6(
    const int* __restrict__ x, const float* __restrict__ h0,
    const float* __restrict__ c0, const float* __restrict__ rec,
    const u16* __restrict__ xz, float* __restrict__ out,
    u32* __restrict__ fastb, u32* __restrict__ slowb) {
  extern __shared__ char sm2[];
  u16* A0 = (u16*)sm2;                 // 8 KB (4096 cells)
  u16* A1 = (u16*)(sm2 + 8192);        // 8 KB
  u32* xmask = (u32*)(sm2 + 16384);    // 1 KB [8][32]
  char* ring = sm2 + 17408;            // 8 slots * 4 KB = 32 KB
  const int tid = threadIdx.x;
  const int wv = tid >> 6, l = tid & 63;
  const int g = blockIdx.x & 7;
  const int r = blockIdx.x >> 3;
  const int Bg = g * 8;
  const int U0 = r * 64;
  const int q = l & 3;
  const int uoff = (l >> 2) & 3;
  const int u0g = U0 + 8 * wv + uoff;
  const int u1g = u0g + 4;
  const int col0 = q * 512 + u0g;
  const int col1 = q * 512 + u1g;
  const int bl = ((l >> 4) << 2) + q;   // 0..15, valid <8 iff l<32
  const int blc = bl & 7;
  const bool act = (l < 32);
  const int b = Bg + blc;
  u32* FP0 = fastb + (g * 2 + 0) * 4096;
  u32* FP1 = fastb + (g * 2 + 1) * 4096;
  u32* SP0 = slowb + (g * 2 + 0) * 4096;
  u32* SP1 = slowb + (g * 2 + 1) * 4096;

  // prime xz ring slots 0..6 (waves 0-3: wave wv stages gate wv, cols U0+l)
  const size_t gofs = ((size_t)(wv * 512 + U0 + l)) * BB + Bg;
  if (wv < 4) {
#pragma unroll
    for (int s = 0; s < 7; ++s)
      __builtin_amdgcn_global_load_lds(
          (AS1 const u32*)(xz + (size_t)s * GG * BB + gofs),
          (AS3 u32*)(ring + s * 4096 + wv * 1024), 16, 0, 0);
  }

  // --- B fragments (R slice) into registers, once ---
  bf16x8 bfr0[16], bfr1[16];
#pragma unroll
  for (int ks = 0; ks < 16; ++ks) {
    int kbase = ks * 32 + ((l >> 4) << 3);
#pragma unroll
    for (int j = 0; j < 8; ++j) {
      bfr0[ks][j] = (short)f2bf(rec[(size_t)(kbase + j) * GG + col0]);
      bfr1[ks][j] = (short)f2bf(rec[(size_t)(kbase + j) * GG + col1]);
    }
  }
  // --- x bitmask for group's 8 batches ---
  if (tid < 256) {
    int bb = tid >> 5, tw = tid & 31;
    u32 mword = 0;
    for (int j = 0; j < 32; ++j)
      mword |= (x[(size_t)(Bg + bb) * TT + tw * 32 + j] != 0 ? 1u : 0u) << j;
    xmask[bb * 32 + tw] = mword;
  }
  float creg0 = c0[(size_t)b * HH + u0g];
  float creg1 = c0[(size_t)b * HH + u1g];
  float hreg0 = h0[(size_t)b * HH + u0g];
  float hreg1 = h0[(size_t)b * HH + u1g];
  // drain prime glls + loads before barrier (slab(0) read precedes stage(0))
  asm volatile("s_waitcnt vmcnt(0) lgkmcnt(0)" ::: "memory");
  __syncthreads();

  // --- publish h(0): 512 cells/WG, tag 1, dual copy ---
  {
    int uu = U0 + (tid >> 3), bl2 = tid & 7;
    u32 cell = ((u32)f2bf(h0[(size_t)(Bg + bl2) * HH + uu]) << 16) | 1u;
    int wp = cellpos8(bl2, uu);
    __hip_atomic_store(&FP0[wp], cell, __ATOMIC_RELAXED,
                       __HIP_MEMORY_SCOPE_WORKGROUP);
    __hip_atomic_store(&SP0[wp], cell, __ATOMIC_RELAXED,
                       __HIP_MEMORY_SCOPE_AGENT);
  }

  const size_t OFS1 = (size_t)BB * TT * HH;
  const size_t OFS2 = OFS1 + (size_t)BB * HH;
  const int pair = (l & 7) | ((l >> 4) << 3);
  u32 mw = 0;

  for (int t = 0; t < TT; ++t) {
    // ---- 1. xz + mask for this step from ring (independent of h) ----
    if ((t & 31) == 0) mw = xmask[blc * 32 + (t >> 5)];
    const bool m = (mw >> (t & 31)) & 1;
    const char* slab = ring + (t & 7) * 4096;
    float xzv[8];
#pragma unroll
    for (int q2 = 0; q2 < 4; ++q2) {
      xzv[q2] = bf2f(*(const u16*)(slab + q2 * 1024 + (8 * wv + uoff) * 16 +
                                   blc * 2));
      xzv[4 + q2] = bf2f(*(const u16*)(slab + q2 * 1024 +
                                       (8 * wv + uoff + 4) * 16 + blc * 2));
    }

    // ---- 2. stage h(t): fast poll + slow merge fallback ----
    const u32 expect = (u32)(t + 1) & 0xffffu;
    const u32* fb = (t & 1) ? FP1 : FP0;
    const u32* sb = (t & 1) ? SP1 : SP0;
    u32x4 v0, v1;
    LOADF(v0, fb + 8 * tid);
    LOADF(v1, fb + 8 * tid + 4);
    WAITV0;
    int tries = 0;
    while (true) {
      int b0 = rowbad(v0, expect), b1 = rowbad(v1, expect);
      if (!__any(b0 | b1)) break;
      int a0 = __any(b0), a1 = __any(b1);
      __builtin_amdgcn_s_sleep(1);
      ++tries;
      if (a0) LOADF(v0, fb + 8 * tid);
      if (a1) LOADF(v1, fb + 8 * tid + 4);
      if (tries >= 3) {
        u32x4 s0, s1;
        if (a0) LOADS(s0, sb + 8 * tid);
        if (a1) LOADS(s1, sb + 8 * tid + 4);
        WAITV0;
        if (a0 && !rowbad(s0, expect)) v0 = s0;
        if (a1 && !rowbad(s1, expect)) v1 = s1;
      } else {
        WAITV0;
      }
    }

    // ---- 3. strip tags -> ping-pong A_lds; one barrier ----
    u16* Ac = (t & 1) ? A1 : A0;
    {
      u32x4 dd;
      dd[0] = (v0[0] >> 16) | (v0[1] & 0xffff0000u);
      dd[1] = (v0[2] >> 16) | (v0[3] & 0xffff0000u);
      dd[2] = (v1[0] >> 16) | (v1[1] & 0xffff0000u);
      dd[3] = (v1[2] >> 16) | (v1[3] & 0xffff0000u);
      *(u32x4*)&Ac[8 * tid] = dd;
    }
    asm volatile("s_waitcnt lgkmcnt(0)" ::: "memory");
    __builtin_amdgcn_s_barrier();
    __builtin_amdgcn_sched_barrier(0);

    // ---- 4. issue xz slab t+7 ----
    if ((t + 7 < TT) && (wv < 4))
      __builtin_amdgcn_global_load_lds(
          (AS1 const u32*)(xz + (size_t)(t + 7) * GG * BB + gofs),
          (AS3 u32*)(ring + ((t + 7) & 7) * 4096 + wv * 1024), 16, 0, 0);

    // ---- 5. A frags + MFMA ----
    bf16x8 af[16];
#pragma unroll
    for (int ks = 0; ks < 16; ++ks)
      af[ks] = *(const bf16x8*)&Ac[(ks * 32 + pair) * 8];
    f32x4 acc0 = {0.f, 0.f, 0.f, 0.f}, acc1 = {0.f, 0.f, 0.f, 0.f};
#pragma unroll
    for (int ks = 0; ks < 16; ++ks) {
      acc0 = __builtin_amdgcn_mfma_f32_16x16x32_bf16(af[ks], bfr0[ks], acc0,
                                                     0, 0, 0);
      acc1 = __builtin_amdgcn_mfma_f32_16x16x32_bf16(af[ks], bfr1[ks], acc1,
                                                     0, 0, 0);
    }

    u32* fn = (t & 1) ? FP0 : FP1;
    u32* sn = (t & 1) ? SP0 : SP1;
    const u32 ntag = (u32)(t + 2) & 0xffffu;
    float hosave[2], cosave[2];

    // ---- 6. transpose dance + gates (lanes>=32 compute garbage, unused) --
#pragma unroll
    for (int ti = 0; ti < 2; ++ti) {
      f32x4 acc = ti ? acc1 : acc0;
      float accLo = (q & 1) ? acc[1] : acc[0];
      float accHi = (q & 1) ? acc[3] : acc[2];
      float sendA = (q & 1) ? acc[0] : acc[1];
      float recvA = __shfl_xor(sendA, 1);
      float sendB = (q & 1) ? acc[2] : acc[3];
      float recvB = __shfl_xor(sendB, 1);
      float k1 = (q & 2) ? accHi : accLo;
      float s2A = (q & 2) ? accLo : accHi;
      float r2A = __shfl_xor(s2A, 2);
      float k2 = (q & 2) ? recvB : recvA;
      float s2B = (q & 2) ? recvA : recvB;
      float r2B = __shfl_xor(s2B, 2);
      float p1 = (q & 1) ? k2 : k1;
      float p2 = (q & 1) ? k1 : k2;
      float p3 = (q & 1) ? r2B : r2A;
      float p4 = (q & 1) ? r2A : r2B;
      float W0 = (q & 2) ? p3 : p1;
      float W1 = (q & 2) ? p4 : p2;
      float W2 = (q & 2) ? p1 : p3;
      float W3 = (q & 2) ? p2 : p4;
      float z0 = W0 + xzv[ti ? 4 : 0];
      float z1 = W1 + xzv[ti ? 5 : 1];
      float z2 = W2 + xzv[ti ? 6 : 2];
      float z3 = W3 + xzv[ti ? 7 : 3];
      float ig = sigm(z0), fg = sigm(z1), gg = tanhfast(z2), og = sigm(z3);
      float cprev = ti ? creg1 : creg0;
      float hprev = ti ? hreg1 : hreg0;
      float cn = fg * cprev + ig * gg;
      float hn = og * tanhfast(cn);
      float ho = m ? hn : hprev;
      float co = m ? cn : cprev;
      if (ti) { creg1 = co; hreg1 = ho; } else { creg0 = co; hreg0 = ho; }
      hosave[ti] = ho; cosave[ti] = co;
      // publish immediately (critical path): dual copy
      if (act && t < TT - 1) {
        const int u = ti ? u1g : u0g;
        u32 cell = ((u32)f2bf(ho) << 16) | ntag;
        int wp = cellpos8(blc, u);
        __hip_atomic_store(&fn[wp], cell, __ATOMIC_RELAXED,
                           __HIP_MEMORY_SCOPE_WORKGROUP);
        __hip_atomic_store(&sn[wp], cell, __ATOMIC_RELAXED,
                           __HIP_MEMORY_SCOPE_AGENT);
      }
    }
    // ---- 7. outputs ----
    if (act) {
      __builtin_nontemporal_store(hosave[0],
                                  &out[((size_t)b * TT + t) * HH + u0g]);
      __builtin_nontemporal_store(hosave[1],
                                  &out[((size_t)b * TT + t) * HH + u1g]);
      if (t == TT - 1) {
        out[OFS1 + (size_t)b * HH + u0g] = hosave[0];
        out[OFS1 + (size_t)b * HH + u1g] = hosave[1];
        out[OFS2 + (size_t)b * HH + u0g] = cosave[0];
        out[OFS2 + (size_t)b * HH + u1g] = cosave[1];
      }
    }
  }
}

// ---------------------------------------------------------------------------
// Fallback (ws too small): round-5 kernel verbatim (proven 4.0 ms).
// ---------------------------------------------------------------------------
__global__ __launch_bounds__(512, 2) void lstm_scan5(
    const int* __restrict__ x, const float* __restrict__ h0,
    const float* __restrict__ c0, const float* __restrict__ rec,
    const u16* __restrict__ xz, float* __restrict__ out,
    u32* __restrict__ hinit, u32* __restrict__ flags) {
  extern __shared__ char sm2[];
  u16* A0 = (u16*)sm2;
  u16* A1 = (u16*)(sm2 + 16384);
  u32* xmask = (u32*)(sm2 + 32768);
  char* ring = sm2 + 34816;
  const int tid = threadIdx.x;
  const int wv = tid >> 6, l = tid & 63;
  const int g = blockIdx.x >> 3;
  const int r = blockIdx.x & 7;
  const int Bg = g * 16;
  const int U0 = r * 64;
  const int q = l & 3;
  const int bl = ((l >> 4) << 2) + q;
  const int b = Bg + bl;
  const int uoff = (l >> 2) & 3;
  const int u0g = U0 + 8 * wv + uoff;
  const int u1g = U0 + 8 * wv + 4 + uoff;
  const int col0 = q * 512 + u0g;
  const int col1 = q * 512 + u1g;
  const int cg = l >> 1;
  const int colL = (cg >> 3) * 512 + U0 + 8 * wv + (cg & 7);
  const size_t gofsL = (size_t)colL * BB + Bg + ((l & 1) << 3);
  char* myslabs = ring + (wv << 10);
#pragma unroll
  for (int s = 0; s < 7; ++s) {
    const u16* gp = xz + (size_t)s * GG * BB + gofsL;
    __builtin_amdgcn_global_load_lds((AS1 const u32*)gp,
                                     (AS3 u32*)(myslabs + s * 8192), 16, 0, 0);
  }
  bf16x8 bfr0[16], bfr1[16];
#pragma unroll
  for (int ks = 0; ks < 16; ++ks) {
    int kbase = ks * 32 + ((l >> 4) << 3);
#pragma unroll
    for (int j = 0; j < 8; ++j) {
      bfr0[ks][j] = (short)f2bf(rec[(size_t)(kbase + j) * GG + col0]);
      bfr1[ks][j] = (short)f2bf(rec[(size_t)(kbase + j) * GG + col1]);
    }
  }
  {
    int bb = tid >> 5, tw = tid & 31;
    u32 mword = 0;
    for (int j = 0; j < 32; ++j)
      mword |= (x[(size_t)(Bg + bb) * TT + tw * 32 + j] != 0 ? 1u : 0u) << j;
    xmask[bb * 32 + tw] = mword;
  }
  float creg0 = c0[(size_t)b * HH + u0g];
  float creg1 = c0[(size_t)b * HH + u1g];
  float hreg0 = h0[(size_t)b * HH + u0g];
  float hreg1 = h0[(size_t)b * HH + u1g];
  __syncthreads();
  const size_t OFS1 = (size_t)BB * TT * HH;
  const size_t OFS2 = OFS1 + (size_t)BB * HH;
  u32* P0 = hinit + g * 8192;
  u32* P1 = (u32*)out + OFS1 + (size_t)g * 8192;
#pragma unroll
  for (int i = 0; i < 2; ++i) {
    int idx = tid + i * 512;
    int uu = U0 + (idx >> 4), bl2 = idx & 15;
    u32 cell = ((u32)f2bf(h0[(size_t)(Bg + bl2) * HH + uu]) << 16) | 1u;
    __hip_atomic_store(&P0[cellpos16(bl2, uu)], cell, __ATOMIC_RELAXED,
                       __HIP_MEMORY_SCOPE_AGENT);
  }
  u32 mw = 0;
  for (int t = 0; t < TT; ++t) {
    const u32 expect = (u32)(t + 1);
    const u32* hb_prev = (t & 1) ? P1 : P0;
    u32x4 v4[4];
#pragma unroll
    for (int rr = 0; rr < 4; ++rr)
      asm volatile("global_load_dwordx4 %0, %1, off sc0 sc1"
                   : "=v"(v4[rr]) : "v"(hb_prev + rr * 2048 + tid * 4));
    asm volatile("s_waitcnt vmcnt(0)" ::: "memory");
    __builtin_amdgcn_sched_barrier(0);
    while (true) {
      u32 sm = 0;
#pragma unroll
      for (int rr = 0; rr < 4; ++rr) {
        u32 bad = ((v4[rr][0] ^ expect) | (v4[rr][1] ^ expect) |
                   (v4[rr][2] ^ expect) | (v4[rr][3] ^ expect)) & 0xffffu;
        sm |= (bad ? 1u : 0u) << rr;
      }
      if (!__any(sm != 0)) break;
      __builtin_amdgcn_s_sleep(1);
#pragma unroll
      for (int rr = 0; rr < 4; ++rr)
        if (__any((sm >> rr) & 1u))
          asm volatile("global_load_dwordx4 %0, %1, off sc0 sc1"
                       : "=v"(v4[rr]) : "v"(hb_prev + rr * 2048 + tid * 4));
      asm volatile("s_waitcnt vmcnt(0)" ::: "memory");
      __builtin_amdgcn_sched_barrier(0);
    }
    u16* Ac = (t & 1) ? A1 : A0;
#pragma unroll
    for (int rr = 0; rr < 4; ++rr) {
      u32x2 dd;
      dd[0] = (v4[rr][0] >> 16) | (v4[rr][1] & 0xffff0000u);
      dd[1] = (v4[rr][2] >> 16) | (v4[rr][3] & 0xffff0000u);
      *(u32x2*)&Ac[rr * 2048 + tid * 4] = dd;
    }
    asm volatile("s_waitcnt lgkmcnt(0)" ::: "memory");
    __builtin_amdgcn_s_barrier();
    __builtin_amdgcn_sched_barrier(0);
    if (t + 7 < TT) {
      const u16* gp = xz + (size_t)(t + 7) * GG * BB + gofsL;
      __builtin_amdgcn_global_load_lds(
          (AS1 const u32*)gp, (AS3 u32*)(myslabs + ((t + 7) & 7) * 8192),
          16, 0, 0);
    }
    bf16x8 af[16];
#pragma unroll
    for (int ks = 0; ks < 16; ++ks)
      af[ks] = *(const bf16x8*)&Ac[(ks * 64 + l) * 8];
    f32x4 acc0 = {0.f, 0.f, 0.f, 0.f}, acc1 = {0.f, 0.f, 0.f, 0.f};
#pragma unroll
    for (int ks = 0; ks < 16; ++ks) {
      acc0 = __builtin_amdgcn_mfma_f32_16x16x32_bf16(af[ks], bfr0[ks], acc0,
                                                     0, 0, 0);
      acc1 = __builtin_amdgcn_mfma_f32_16x16x32_bf16(af[ks], bfr1[ks], acc1,
                                                     0, 0, 0);
    }
    if ((t & 31) == 0) mw = xmask[bl * 32 + (t >> 5)];
    const bool m = (mw >> (t & 31)) & 1;
    const char* slab = ring + (((t & 7) * 8 + wv) << 10);
    float xzv[8];
#pragma unroll
    for (int g2 = 0; g2 < 4; ++g2) {
      xzv[g2] = bf2f(*(const u16*)(
          slab + (((g2 * 8 + uoff) * 2 + (bl >> 3)) << 4) + ((bl & 7) << 1)));
      xzv[4 + g2] = bf2f(*(const u16*)(
          slab + (((g2 * 8 + 4 + uoff) * 2 + (bl >> 3)) << 4) +
          ((bl & 7) << 1)));
    }
    u32* hb_next = (t & 1) ? P0 : P1;
    const u32 ntag = (u32)(t + 2);
    float hosave[2], cosave[2];
#pragma unroll
    for (int ti = 0; ti < 2; ++ti) {
      f32x4 acc = ti ? acc1 : acc0;
      float accLo = (q & 1) ? acc[1] : acc[0];
      float accHi = (q & 1) ? acc[3] : acc[2];
      float sendA = (q & 1) ? acc[0] : acc[1];
      float recvA = __shfl_xor(sendA, 1);
      float sendB = (q & 1) ? acc[2] : acc[3];
      float recvB = __shfl_xor(sendB, 1);
      float k1 = (q & 2) ? accHi : accLo;
      float s2A = (q & 2) ? accLo : accHi;
      float r2A = __shfl_xor(s2A, 2);
      float k2 = (q & 2) ? recvB : recvA;
      float s2B = (q & 2) ? recvA : recvB;
      float r2B = __shfl_xor(s2B, 2);
      float p1 = (q & 1) ? k2 : k1;
      float p2 = (q & 1) ? k1 : k2;
      float p3 = (q & 1) ? r2B : r2A;
      float p4 = (q & 1) ? r2A : r2B;
      float W0 = (q & 2) ? p3 : p1;
      float W1 = (q & 2) ? p4 : p2;
      float W2 = (q & 2) ? p1 : p3;
      float W3 = (q & 2) ? p2 : p4;
      float z0 = W0 + xzv[ti ? 4 : 0];
      float z1 = W1 + xzv[ti ? 5 : 1];
      float z2 = W2 + xzv[ti ? 6 : 2];
      float z3 = W3 + xzv[ti ? 7 : 3];
      float ig = sigm(z0), fg = sigm(z1), gg = tanhfast(z2), og = sigm(z3);
      float cprev = ti ? creg1 : creg0;
      float hprev = ti ? hreg1 : hreg0;
      float cn = fg * cprev + ig * gg;
      float hn = og * tanhfast(cn);
      float ho = m ? hn : hprev;
      float co = m ? cn : cprev;
      if (ti) { creg1 = co; hreg1 = ho; } else { creg0 = co; hreg0 = ho; }
      hosave[ti] = ho; cosave[ti] = co;
      if (t < TT - 1) {
        const int u = ti ? u1g : u0g;
        u32 cell = ((u32)f2bf(ho) << 16) | ntag;
        __hip_atomic_store(&hb_next[cellpos16(bl, u)], cell, __ATOMIC_RELAXED,
                           __HIP_MEMORY_SCOPE_AGENT);
      }
    }
    __builtin_nontemporal_store(hosave[0],
                                &out[((size_t)b * TT + t) * HH + u0g]);
    __builtin_nontemporal_store(hosave[1],
                                &out[((size_t)b * TT + t) * HH + u1g]);
    if (t == TT - 1) {
      out[OFS2 + (size_t)b * HH + u0g] = cosave[0];
      out[OFS2 + (size_t)b * HH + u1g] = cosave[1];
      if (tid == 0)
        __hip_atomic_store(&flags[(g * 8 + r) * 16], 1u, __ATOMIC_RELEASE,
                           __HIP_MEMORY_SCOPE_AGENT);
      while (true) {
        u32 f = 1u;
        if (l < 8)
          f = __hip_atomic_load(&flags[(g * 8 + l) * 16], __ATOMIC_ACQUIRE,
                                __HIP_MEMORY_SCOPE_AGENT);
        if (__all(f >= 1u)) break;
        __builtin_amdgcn_s_sleep(2);
      }
      out[OFS1 + (size_t)b * HH + u0g] = hosave[0];
      out[OFS1 + (size_t)b * HH + u1g] = hosave[1];
    }
  }
}

// ---------------------------------------------------------------------------
extern "C" void kernel_launch(void* const* d_in, const int* in_sizes, int n_in,
                              void* d_out, int out_size, void* d_ws,
                              size_t ws_size, hipStream_t stream) {
  const int* x = (const int*)d_in[0];
  const float* h0 = (const float*)d_in[1];
  const float* c0 = (const float*)d_in[2];
  const float* emb = (const float*)d_in[3];
  const float* Wk = (const float*)d_in[4];
  const float* rec = (const float*)d_in[5];
  const float* bias = (const float*)d_in[6];
  float* out = (float*)d_out;
  char* ws = (char*)d_ws;

  const size_t XZ_BYTES = (size_t)TT * GG * BB * 2;  // 256 MiB
  u16* xz = (u16*)ws;

  hipFuncSetAttribute((const void*)xz_gemm_mfma,
                      hipFuncAttributeMaxDynamicSharedMemorySize, 131072);

  if (ws_size >= XZ_BYTES + 524288) {
    // round-6 path: dedicated fast+slow exchange buffers (512 KB)
    u32* fastb = (u32*)(ws + XZ_BYTES);            // 256 KB
    u32* slowb = (u32*)(ws + XZ_BYTES + 262144);   // 256 KB
    hipMemsetAsync(fastb, 0, 524288, stream);
    xz_gemm_mfma<<<TT, 256, 131072, stream>>>(x, emb, Wk, bias, xz);
    hipFuncSetAttribute((const void*)lstm_scan6,
                        hipFuncAttributeMaxDynamicSharedMemorySize, 50176);
    lstm_scan6<<<64, 512, 50176, stream>>>(x, h0, c0, rec, xz, out, fastb,
                                           slowb);
  } else {
    // round-5 fallback (proven): hinit + flags in ws, P1 in out hT region
    u32* hinit = (u32*)(ws + XZ_BYTES);
    u32* flags = (u32*)(ws + XZ_BYTES + 131072);
    if (ws_size < XZ_BYTES + 133120) return;
    const size_t OFS1 = (size_t)BB * TT * HH;
    hipMemsetAsync(hinit, 0, 131072, stream);
    hipMemsetAsync(flags, 0, 2048, stream);
    hipMemsetAsync((char*)d_out + OFS1 * 4, 0, 131072, stream);
    xz_gemm_mfma<<<TT, 256, 131072, stream>>>(x, emb, Wk, bias, xz);
    hipFuncSetAttribute((const void*)lstm_scan5,
                        hipFuncAttributeMaxDynamicSharedMemorySize, 100352);
    lstm_scan5<<<32, 512, 100352, stream>>>(x, h0, c0, rec, xz, out, hinit,
                                            flags);
  }
}